// Round 7
// baseline (99.785 us; speedup 1.0000x reference)
//
#include <hip/hip_runtime.h>

// Problem constants (match reference)
#define B_   16
#define N_   65536
#define G_   64
#define M_   (N_ + G_)       // 65600 rois per batch (rois + appended gt)
#define R_   128             // ROIS_PER_IMAGE
#define FGP  32              // FG_PER_IMAGE
#define NB_  16384           // buckets for rank selection over u_perm in [0,1)
#define NCH_ 32              // coarse chunks per row
#define CHUNK_ (NB_ / NCH_)  // 512
#define NROW_ (B_ * 2)       // (batch, class) rows
#define FW_  (NB_ / 32)      // flag words per row = 512

// ---------------------------------------------------------------------------
// K0: GT table as AoS float4 {x1,y1,x2,y2} (+poison for gt_zero rows) + area,
//     plus per-batch jmax = round8(last non-gz row + 1). One wave == one batch
//     (G_==64), so trailing-gz detection is a single ballot.
// ---------------------------------------------------------------------------
__global__ void prep_kernel(const float* __restrict__ gt_boxes,
                            float4* __restrict__ gt4,
                            float*  __restrict__ garea,
                            int*    __restrict__ jmax)
{
    int t = blockIdx.x * blockDim.x + threadIdx.x;
    if (t >= B_ * G_) return;
    int b = t / G_, j = t % G_;
    const float* g = gt_boxes + t * 6;
    float x1 = g[0], y1 = g[1], x2 = g[2], y2 = g[3];
    float gw = x2 - x1 + 1.0f, gh = y2 - y1 + 1.0f;
    bool gz = (gw == 1.0f) && (gh == 1.0f);
    gt4[t] = gz ? make_float4(3.0e8f, 3.0e8f, -3.0e8f, -3.0e8f)
                : make_float4(x1, y1, x2, y2);
    garea[t] = gw * gh;                       // == 1.0 for gz rows

    unsigned long long alive = __ballot(!gz); // lane == j within this batch
    if (j == 0) {
        int last = 63 - __clzll(alive);       // -1 if none alive
        jmax[b] = (last + 1 + 7) & ~7;        // multiple of 8, 0..64
    }
}

// ---------------------------------------------------------------------------
// K1: per-roi rational IoU max (Dekker two-product lex compare, value-exact),
//     one IEEE divide at the end; classification + bucket histogram.
//     GT operands broadcast from LDS (ds_read_b128 + b32 per j).
// ---------------------------------------------------------------------------
__global__ void iou_kernel(const float* __restrict__ all_rois,
                           const float* __restrict__ gt_boxes,
                           const float4* __restrict__ gt4,
                           const float*  __restrict__ garea,
                           const int*    __restrict__ jmax,
                           const float*  __restrict__ u_perm,
                           unsigned*     __restrict__ packed,
                           int*          __restrict__ hist)
{
    __shared__ float4 sg[G_];
    __shared__ float  sa[G_];
    const int b   = blockIdx.y;
    const int tid = threadIdx.x;
    if (tid < G_) { sg[tid] = gt4[b * G_ + tid]; sa[tid] = garea[b * G_ + tid]; }
    __syncthreads();

    const int i = blockIdx.x * blockDim.x + tid;
    if (i >= M_) return;

    float x1, y1, x2, y2;
    if (i < N_) {
        const float* p = all_rois + ((size_t)b * N_ + i) * 5;
        x1 = p[1]; y1 = p[2]; x2 = p[3]; y2 = p[4];
    } else {
        const float* p = gt_boxes + (b * G_ + (i - N_)) * 6;
        x1 = p[0]; y1 = p[1]; x2 = p[2]; y2 = p[3];
    }
    float aw = x2 - x1 + 1.0f, ah = y2 - y1 + 1.0f;
    float area_a = aw * ah;
    bool  a_zero = (aw == 1.0f) && (ah == 1.0f);

    const int jm = jmax[b];               // uniform; trailing gz rows skipped
    float ib = 0.0f, ub = 1.0f;           // rational best = 0/1
    for (int jj = 0; jj < jm; jj += 8) {
        #pragma unroll
        for (int k = 0; k < 8; ++k) {
            const int j = jj + k;
            const float4 g  = sg[j];
            const float  ga = sa[j];
            float iw = fmaxf(fminf(x2, g.z) - fmaxf(x1, g.x) + 1.0f, 0.0f);
            float ih = fmaxf(fminf(y2, g.w) - fmaxf(y1, g.y) + 1.0f, 0.0f);
            float inter = iw * ih;
            float uni   = area_a + ga - inter;           // > 0 always
            float hi1 = inter * ub;
            float lo1 = fmaf(inter, ub, -hi1);           // exact residual
            float hi2 = ib * uni;
            float lo2 = fmaf(ib, uni, -hi2);             // exact residual
            bool gt = (hi1 > hi2) || ((hi1 == hi2) && (lo1 > lo2));
            if (gt) { ib = inter; ub = uni; }            // ties keep first
        }
    }
    float best = ib / ub;          // correctly-rounded rational max == ref max
    if (a_zero) best = -1.0f;      // a_zero overrides everything

    bool fg = best >= 0.7f;
    bool bg = best < 0.3f;         // == ((mo<0.3)&(mo>=0)) | (mo<0)
    unsigned pk = 0xFFFFFFFFu;
    if (fg || bg) {
        int cls = fg ? 0 : 1;
        float u = u_perm[(size_t)b * M_ + i];
        int bucket = min(max((int)(u * (float)NB_), 0), NB_ - 1);  // pow2 scale
        pk = ((unsigned)cls << 16) | (unsigned)bucket;
        atomicAdd(&hist[(size_t)(b * 2 + cls) * NB_ + bucket], 1);
    }
    packed[(size_t)b * M_ + i] = pk;
}

// ---------------------------------------------------------------------------
// K2: one block (512 thr) per (batch,class) row: exclusive prefix over 16384
//     bins in place; shfl-based wave scan (2 barriers). Emits coarse inclusive
//     chunk sums (32/row) and row total (= fg_num / bg_num).
// ---------------------------------------------------------------------------
__global__ void scan_row(int* __restrict__ hist,
                         int* __restrict__ coarse,
                         int* __restrict__ cnt)
{
    __shared__ int wt[8], wbase[8];
    const int row = blockIdx.x, t = threadIdx.x;   // 512 threads
    const int lane = t & 63, w = t >> 6;
    int4* h4 = (int4*)(hist + (size_t)row * NB_ + t * 32);
    int v[32];
    #pragma unroll
    for (int k = 0; k < 8; ++k) {
        int4 x4 = h4[k];
        v[k * 4 + 0] = x4.x; v[k * 4 + 1] = x4.y;
        v[k * 4 + 2] = x4.z; v[k * 4 + 3] = x4.w;
    }
    int run = 0;
    #pragma unroll
    for (int k = 0; k < 32; ++k) { int x = v[k]; v[k] = run; run += x; }
    int x = run;                                   // wave-inclusive scan of run
    #pragma unroll
    for (int d = 1; d < 64; d <<= 1) {
        int y = __shfl_up(x, d);
        if (lane >= d) x += y;
    }
    if (lane == 63) wt[w] = x;
    __syncthreads();
    if (t == 0) {
        int acc = 0;
        #pragma unroll
        for (int q = 0; q < 8; ++q) { wbase[q] = acc; acc += wt[q]; }
    }
    __syncthreads();
    const int incl  = wbase[w] + x;                // thread-inclusive, global
    const int texcl = incl - run;                  // thread-exclusive base
    if ((t & 15) == 15) coarse[row * NCH_ + (t >> 4)] = incl;
    if (t == 511) cnt[row] = incl;
    #pragma unroll
    for (int k = 0; k < 8; ++k) {
        int4 x4;
        x4.x = v[k * 4 + 0] + texcl; x4.y = v[k * 4 + 1] + texcl;
        x4.z = v[k * 4 + 2] + texcl; x4.w = v[k * 4 + 3] + texcl;
        h4[k] = x4;
    }
}

// ---------------------------------------------------------------------------
// K3: per (batch,pos): rank -> bucket (coarse LDS walk + binsearch), set
//     bucket flag bit, store {start, cnt, r}. Runs on pristine EXCLUSIVE hist.
// ---------------------------------------------------------------------------
__global__ void flag_kernel(const float* __restrict__ u_fg,
                            const float* __restrict__ u_bg,
                            const int*  __restrict__ cnt,
                            const int*  __restrict__ coarse,
                            const int*  __restrict__ E,      // hist (exclusive)
                            unsigned*   __restrict__ flags,
                            int4*       __restrict__ pick)
{
    __shared__ int sc[2 * NCH_];
    const int b = blockIdx.x;
    const int pos = threadIdx.x;    // 128
    if (pos < 2 * NCH_) sc[pos] = coarse[(b * 2) * NCH_ + pos];
    __syncthreads();

    const int fgn = cnt[b * 2 + 0];
    const int bgn = cnt[b * 2 + 1];
    const bool both    = (fgn > 0) && (bgn > 0);
    const bool only_fg = (fgn > 0) && (bgn == 0);
    const int fg_this  = both ? min(FGP, fgn) : (only_fg ? R_ : 0);
    const bool is_fg   = pos < fg_this;

    int cls, rank, cnum;
    if (is_fg) {
        cls = 0; cnum = fgn;
        if (only_fg) {
            float uf = u_fg[b * R_ + pos];
            int kk = (int)(uf * (float)fgn);               // trunc toward zero
            rank = min(max(kk, 0), max(fgn - 1, 0));
        } else {
            rank = pos;
        }
    } else {
        cls = 1; cnum = bgn;
        float ubv = u_bg[b * R_ + pos];
        int kk = (int)(ubv * (float)bgn);
        rank = min(max(kk, 0), max(bgn - 1, 0));
    }

    int4 pk4 = make_int4(0, 0, 0, 0);    // cnt==0 sentinel
    if (cnum > 0) {
        const int row = b * 2 + cls;
        const int* sce = sc + cls * NCH_;
        int c = 0;                        // first chunk with incl > rank
        while (c < NCH_ - 1 && sce[c] <= rank) ++c;
        const int* Er = E + (size_t)row * NB_;
        int lo = c * CHUNK_, hi = c * CHUNK_ + CHUNK_ - 1;
        while (lo < hi) {                 // max j with Er[j] <= rank
            int mid = (lo + hi + 1) >> 1;
            if (Er[mid] <= rank) lo = mid; else hi = mid - 1;
        }
        const int start = Er[lo];
        const int next  = (lo < NB_ - 1) ? Er[lo + 1] : cnum;
        atomicOr(&flags[row * FW_ + (lo >> 5)], 1u << (lo & 31));
        pk4 = make_int4(start, next - start, rank - start, lo);
    }
    pick[b * R_ + pos] = pk4;
}

// ---------------------------------------------------------------------------
// K4: scatter ONLY elements whose bucket is flagged (~0.2%) -> tiny writes.
// ---------------------------------------------------------------------------
__global__ void scatter_kernel(const unsigned* __restrict__ packed,
                               const unsigned* __restrict__ flags,
                               int*            __restrict__ E,
                               int*            __restrict__ buckets)
{
    const int b = blockIdx.y;
    const int i = blockIdx.x * blockDim.x + threadIdx.x;
    if (i >= M_) return;
    unsigned pk = packed[(size_t)b * M_ + i];
    if (pk == 0xFFFFFFFFu) return;
    const int cls = (int)(pk >> 16);
    const int bucket = (int)(pk & 0xFFFFu);
    const int row = b * 2 + cls;
    unsigned w = flags[row * FW_ + (bucket >> 5)];     // 4KB/batch: L1-hot
    if (!(w & (1u << (bucket & 31)))) return;
    int p = atomicAdd(&E[(size_t)row * NB_ + bucket], 1);
    buckets[(size_t)row * M_ + p] = i;
}

// ---------------------------------------------------------------------------
// K5: stable (u, idx) rank-selection among bucket members, gather outputs,
//     lazy argmax (reference divide semantics) for picked fg rois only.
// ---------------------------------------------------------------------------
__global__ void sample_kernel(const float* __restrict__ all_rois,
                              const float* __restrict__ gt_boxes,
                              const float4* __restrict__ gt4,
                              const float*  __restrict__ garea,
                              const float* __restrict__ u_perm,
                              const int*  __restrict__ cnt,
                              const int4* __restrict__ pick,
                              const int*  __restrict__ buckets,
                              float*      __restrict__ out)
{
    const int b   = blockIdx.x;
    const int pos = threadIdx.x;   // 128
    const int fgn = cnt[b * 2 + 0];
    const int bgn = cnt[b * 2 + 1];
    const bool both    = (fgn > 0) && (bgn > 0);
    const bool only_fg = (fgn > 0) && (bgn == 0);
    const int fg_this  = both ? min(FGP, fgn) : (only_fg ? R_ : 0);
    const bool is_fg   = pos < fg_this;
    const int cls  = is_fg ? 0 : 1;

    const int4 pk = pick[b * R_ + pos];
    int keep = 0;                  // cnum==0 edge: argsort(all 2.0)[0] == 0
    if (pk.y > 0) {
        const int row = b * 2 + cls;
        const int*   be = buckets + (size_t)row * M_ + pk.x;
        const float* up = u_perm + (size_t)b * M_;
        const int cnt2 = pk.y, r = pk.z;
        for (int t2 = 0; t2 < cnt2; ++t2) {
            int it = be[t2]; float ut = up[it];
            int rk = 0;
            for (int s2 = 0; s2 < cnt2; ++s2) {
                if (s2 == t2) continue;
                int is2 = be[s2]; float us = up[is2];
                if (us < ut || (us == ut && is2 < it)) rk++;
            }
            if (rk == r) { keep = it; break; }
        }
    }

    // gather roi coords
    float ox1, oy1, ox2, oy2;
    if (keep < N_) {
        const float* p = all_rois + ((size_t)b * N_ + keep) * 5;
        ox1 = p[1]; oy1 = p[2]; ox2 = p[3]; oy2 = p[4];
    } else {
        const float* p = gt_boxes + (b * G_ + (keep - N_)) * 6;
        ox1 = p[0]; oy1 = p[1]; ox2 = p[2]; oy2 = p[3];
    }
    float* ro = out + ((size_t)b * R_ + pos) * 5;
    ro[0] = (float)b; ro[1] = ox1; ro[2] = oy1; ro[3] = ox2; ro[4] = oy2;

    // lazy argmax with exact reference semantics (fg picks only)
    float lab = 0.0f, tidv = -1.0f;
    if (is_fg) {
        float aw = ox2 - ox1 + 1.0f, ah = oy2 - oy1 + 1.0f;
        float area_a = aw * ah;
        float best = -1e30f;
        int   bi   = 0;
        for (int j = 0; j < G_; ++j) {
            const float4 g  = gt4[b * G_ + j];
            const float  ga = garea[b * G_ + j];
            float iw = fmaxf(fminf(ox2, g.z) - fmaxf(ox1, g.x) + 1.0f, 0.0f);
            float ih = fmaxf(fminf(oy2, g.w) - fmaxf(oy1, g.y) + 1.0f, 0.0f);
            float inter = iw * ih;
            float ov = inter / (area_a + ga - inter);  // IEEE div
            if (ov > best) { best = ov; bi = j; }      // first-max
        }
        lab  = gt_boxes[(b * G_ + bi) * 6 + 4];
        tidv = gt_boxes[(b * G_ + bi) * 6 + 5];
    }
    float* olab = out + (size_t)B_ * R_ * 5;
    float* otid = olab + (size_t)B_ * R_;
    olab[b * R_ + pos] = lab;
    otid[b * R_ + pos] = tidv;
}

// ---------------------------------------------------------------------------
extern "C" void kernel_launch(void* const* d_in, const int* in_sizes, int n_in,
                              void* d_out, int out_size, void* d_ws, size_t ws_size,
                              hipStream_t stream)
{
    const float* all_rois = (const float*)d_in[0];
    const float* gt_boxes = (const float*)d_in[1];
    const float* u_perm   = (const float*)d_in[2];
    const float* u_fg     = (const float*)d_in[3];
    const float* u_bg     = (const float*)d_in[4];
    float* out = (float*)d_out;

    // workspace layout (4B elems); ~15 MB total
    int*      hist    = (int*)d_ws;                               // NROW*NB
    unsigned* flags   = (unsigned*)(hist + (size_t)NROW_ * NB_);  // NROW*FW
    int*      cnt     = (int*)(flags + NROW_ * FW_);              // 32
    int*      coarse  = cnt + 32;                                 // NROW*NCH
    int4*     pick    = (int4*)(coarse + NROW_ * NCH_);           // B*R int4
    unsigned* packed  = (unsigned*)(pick + B_ * R_);              // B*M
    int*      buckets = (int*)(packed + (size_t)B_ * M_);         // NROW*M
    float4*   gt4     = (float4*)(buckets + (size_t)NROW_ * M_);  // B*G float4
    float*    garea   = (float*)(gt4 + B_ * G_);                  // B*G
    int*      jmax    = (int*)(garea + B_ * G_);                  // B

    // zero hist + flags (contiguous at front)
    hipMemsetAsync(d_ws, 0, (size_t)(NROW_ * NB_ + NROW_ * FW_) * sizeof(int), stream);

    prep_kernel<<<(B_ * G_ + 255) / 256, 256, 0, stream>>>(gt_boxes, gt4, garea, jmax);

    dim3 grid1((M_ + 255) / 256, B_);
    iou_kernel<<<grid1, 256, 0, stream>>>(all_rois, gt_boxes, gt4, garea, jmax,
                                          u_perm, packed, hist);
    scan_row<<<NROW_, 512, 0, stream>>>(hist, coarse, cnt);
    flag_kernel<<<B_, R_, 0, stream>>>(u_fg, u_bg, cnt, coarse, hist, flags, pick);
    scatter_kernel<<<grid1, 256, 0, stream>>>(packed, flags, hist, buckets);
    sample_kernel<<<B_, R_, 0, stream>>>(all_rois, gt_boxes, gt4, garea, u_perm,
                                         cnt, pick, buckets, out);
}